// Round 13
// baseline (296.506 us; speedup 1.0000x reference)
//
#include <hip/hip_runtime.h>
#include <hip/hip_fp16.h>

#define D     2048
#define EPSV  1e-5f

typedef _Float16 h2 __attribute__((ext_vector_type(2)));

__device__ __forceinline__ unsigned int pkh(float a, float b) {
    return __builtin_bit_cast(unsigned int, __builtin_amdgcn_cvt_pkrtz(a, b));
}
__device__ __forceinline__ h2 ash2(unsigned int u) {
    return __builtin_bit_cast(h2, u);
}

// DPP row_shr:N add (old=0 -> lanes with no source contribute 0)
template<int CTRL>
__device__ __forceinline__ float dppadd(float x) {
    int y = __builtin_amdgcn_update_dpp(0, __builtin_bit_cast(int, x), CTRL, 0xf, 0xf, false);
    return x + __builtin_bit_cast(float, y);
}
// full wave64 sum; result valid in lanes 15,31,47,63
__device__ __forceinline__ float wave_sum(float x) {
    x += __shfl_xor(x, 32, 64);
    x += __shfl_xor(x, 16, 64);
    x = dppadd<0x111>(x);
    x = dppadd<0x112>(x);
    x = dppadd<0x114>(x);
    x = dppadd<0x118>(x);
    return x;
}

__device__ __forceinline__ float rdlane(float v, int l) {
    return __builtin_bit_cast(float, __builtin_amdgcn_readlane(__builtin_bit_cast(int, v), l));
}

// fast tanh: 1 - 2/(e^{2x}+1); v_exp-based, ample precision for 0.24 threshold
__device__ __forceinline__ float ftanh(float x) {
    float xc = fminf(fmaxf(x, -10.f), 10.f);
    float e  = __expf(2.f * xc);
    return 1.f - 2.f * __builtin_amdgcn_rcpf(e + 1.f);
}

// ---- weight prep: Wq[c][p] = packed f16 pair of column c at d={2p,2p+1}
// c: 0-3 Wb, 4-7 Wm, 8-23 Wr(i*4+j). Grid: 24 blocks x 256 threads.
__global__ __launch_bounds__(256) void wt_kernel(
    const float* __restrict__ Wb, const float* __restrict__ Wm,
    const float* __restrict__ Wr, unsigned int* __restrict__ Wq)
{
    const int c = blockIdx.x;
    const int t = threadIdx.x;
    const float* src;
    int stride;
    if (c < 4)       { src = Wb + c;       stride = 4;  }
    else if (c < 8)  { src = Wm + (c - 4); stride = 4;  }
    else             { src = Wr + (c - 8); stride = 16; }

    #pragma unroll
    for (int k = 0; k < 4; ++k) {
        int p = t + 256 * k;                    // pair index 0..1023
        float a = src[(2 * p)     * stride];
        float b = src[(2 * p + 1) * stride];
        Wq[c * 1024 + p] = pkh(a, b);
    }
}

// one wave == one token; zero barriers, zero LDS
__global__ __launch_bounds__(256) void hc_kernel(
    const float* __restrict__ lo,      // [tok, D]
    const float* __restrict__ hs,      // [tok, 4, D]
    const float* __restrict__ Bm,      // [1,4]
    const float* __restrict__ Am,      // [4,1]
    const float* __restrict__ Ar,      // [4,4]
    const float* __restrict__ s_alpha, // [4,4]
    const float* __restrict__ s_beta,  // [1,4]
    const unsigned int* __restrict__ Wq, // [24][1024] packed f16 weight pairs
    float* __restrict__ out)           // [tok, 4, D]
{
    const int tid  = threadIdx.x;
    const int wave = tid >> 6;
    const int lane = tid & 63;
    const long tok = (long)blockIdx.x * 4 + wave;

    const float4* hs4  = (const float4*)(hs + tok * (long)(4 * D));
    const float4* lo4  = (const float4*)(lo + tok * (long)D);
    float4*       out4 = (float4*)(out + tok * (long)(4 * D));

    // ---- Pass 1: per-row stats (read rows lane-contiguously, wave-reduce) ----
    float mu[4], rs[4];
    #pragma unroll
    for (int n = 0; n < 4; ++n) {
        float s = 0.f, q = 0.f;
        #pragma unroll
        for (int k = 0; k < 8; ++k) {
            float4 v = hs4[n * 512 + k * 64 + lane];
            s += v.x + v.y + v.z + v.w;
            q += v.x * v.x + v.y * v.y + v.z * v.z + v.w * v.w;
        }
        s = wave_sum(s);
        q = wave_sum(q);
        float st = rdlane(s, 15), qt = rdlane(q, 15);
        float m  = st * (1.f / D);
        mu[n] = m;
        rs[n] = rsqrtf(qt * (1.f / D) - m * m + EPSV);
    }

    // ---- Pass 2: H_bar on the fly (rows re-read: L2-hot), 24 dots in f16 ----
    float acc[24];
    #pragma unroll
    for (int c = 0; c < 24; ++c) acc[c] = 0.f;

    const uint2* Wq2 = (const uint2*)Wq;   // [24][512] uint2 (4 bf16... f16 pairs)

    #pragma unroll
    for (int k = 0; k < 8; ++k) {
        int i4 = k * 64 + lane;            // float4 chunk id, lane-contiguous
        float4 v0 = hs4[0 * 512 + i4];
        float4 v1 = hs4[1 * 512 + i4];
        float4 v2 = hs4[2 * 512 + i4];
        float4 v3 = hs4[3 * 512 + i4];
        float hbx = 0.25f * ((v0.x - mu[0]) * rs[0] + (v1.x - mu[1]) * rs[1] +
                             (v2.x - mu[2]) * rs[2] + (v3.x - mu[3]) * rs[3]);
        float hby = 0.25f * ((v0.y - mu[0]) * rs[0] + (v1.y - mu[1]) * rs[1] +
                             (v2.y - mu[2]) * rs[2] + (v3.y - mu[3]) * rs[3]);
        float hbz = 0.25f * ((v0.z - mu[0]) * rs[0] + (v1.z - mu[1]) * rs[1] +
                             (v2.z - mu[2]) * rs[2] + (v3.z - mu[3]) * rs[3]);
        float hbw = 0.25f * ((v0.w - mu[0]) * rs[0] + (v1.w - mu[1]) * rs[1] +
                             (v2.w - mu[2]) * rs[2] + (v3.w - mu[3]) * rs[3]);
        h2 plo = ash2(pkh(hbx, hby));
        h2 phi = ash2(pkh(hbz, hbw));
        #pragma unroll
        for (int c = 0; c < 24; ++c) {
            uint2 w = Wq2[c * 512 + i4];
            acc[c] = __builtin_amdgcn_fdot2(plo, ash2(w.x), acc[c], false);
            acc[c] = __builtin_amdgcn_fdot2(phi, ash2(w.y), acc[c], false);
        }
    }

    // ---- Combine: wave-reduce 24 dots, tanh+affine, broadcast via readlane ----
    #pragma unroll
    for (int c = 0; c < 24; ++c) acc[c] = wave_sum(acc[c]);

    float coef[24];
    #pragma unroll
    for (int c = 0; c < 24; ++c) {
        float R = rdlane(acc[c], 15);
        float t = ftanh(R);
        float cv;
        if (c < 4)      cv = s_beta[c] * t + Bm[c];
        else if (c < 8) cv = s_alpha[(c - 4) * 4] * t + Am[c - 4];
        else            cv = s_alpha[c - 8] * t + Ar[c - 8];
        coef[c] = cv;
    }

    // ---- Pass 3: outputs from f32 re-read (L2/L3-hot) + lo ----
    #pragma unroll
    for (int k = 0; k < 8; ++k) {
        int i4 = k * 64 + lane;
        float4 v0 = hs4[0 * 512 + i4];
        float4 v1 = hs4[1 * 512 + i4];
        float4 v2 = hs4[2 * 512 + i4];
        float4 v3 = hs4[3 * 512 + i4];
        float4 lv = lo4[i4];

        float4 mx;
        mx.x = coef[4] * v0.x + coef[5] * v1.x + coef[6] * v2.x + coef[7] * v3.x;
        mx.y = coef[4] * v0.y + coef[5] * v1.y + coef[6] * v2.y + coef[7] * v3.y;
        mx.z = coef[4] * v0.z + coef[5] * v1.z + coef[6] * v2.z + coef[7] * v3.z;
        mx.w = coef[4] * v0.w + coef[5] * v1.w + coef[6] * v2.w + coef[7] * v3.w;

        #pragma unroll
        for (int i = 0; i < 4; ++i) {
            float a0 = coef[8 + i * 4 + 0];
            float a1 = coef[8 + i * 4 + 1];
            float a2 = coef[8 + i * 4 + 2];
            float a3 = coef[8 + i * 4 + 3];
            float bd = coef[i];
            float4 o;
            o.x = bd * lv.x + mx.x + a0 * v0.x + a1 * v1.x + a2 * v2.x + a3 * v3.x;
            o.y = bd * lv.y + mx.y + a0 * v0.y + a1 * v1.y + a2 * v2.y + a3 * v3.y;
            o.z = bd * lv.z + mx.z + a0 * v0.z + a1 * v1.z + a2 * v2.z + a3 * v3.z;
            o.w = bd * lv.w + mx.w + a0 * v0.w + a1 * v1.w + a2 * v2.w + a3 * v3.w;
            out4[i * 512 + i4] = o;
        }
    }
}

extern "C" void kernel_launch(void* const* d_in, const int* in_sizes, int n_in,
                              void* d_out, int out_size, void* d_ws, size_t ws_size,
                              hipStream_t stream) {
    const float* lo      = (const float*)d_in[0];
    const float* hs      = (const float*)d_in[1];
    const float* Bm      = (const float*)d_in[2];
    const float* Am      = (const float*)d_in[3];
    const float* Ar      = (const float*)d_in[4];
    const float* s_alpha = (const float*)d_in[5];
    const float* s_beta  = (const float*)d_in[6];
    const float* Wb      = (const float*)d_in[7];
    const float* Wm      = (const float*)d_in[8];
    const float* Wr      = (const float*)d_in[9];
    float* out = (float*)d_out;

    unsigned int* Wq = (unsigned int*)d_ws;        // 98304 B

    wt_kernel<<<24, 256, 0, stream>>>(Wb, Wm, Wr, Wq);

    const int tokens = in_sizes[0] / D;            // 8192
    hc_kernel<<<tokens / 4, 256, 0, stream>>>(lo, hs, Bm, Am, Ar, s_alpha, s_beta,
                                              Wq, out);
}